// Round 2
// baseline (453.324 us; speedup 1.0000x reference)
//
#include <hip/hip_runtime.h>
#include <cstdint>
#include <cstddef>

// ---------------- problem constants ----------------
#define SCALEQ 0.17677669529663689f // 32^-0.5

typedef _Float16 half_t;
typedef _Float16 half8   __attribute__((ext_vector_type(8)));
typedef _Float16 half4v  __attribute__((ext_vector_type(4)));
typedef float    float4v __attribute__((ext_vector_type(4)));

#define GLDS16(gp, lp)                                                        \
  __builtin_amdgcn_global_load_lds(                                           \
      (const __attribute__((address_space(1))) void*)(gp),                    \
      (__attribute__((address_space(3))) void*)(lp), 16, 0, 0)

// ---------------- prep kernels (unchanged from round 1) ----------------
__global__ void prep_convw(const float* __restrict__ w, half_t* __restrict__ Wt) {
  int idx = blockIdx.x * 256 + threadIdx.x;           // < 589824
  int tap = idx >> 16, rem = idx & 65535;
  int o = rem >> 8, c = rem & 255;
  Wt[idx] = (half_t)w[(o * 256 + c) * 9 + tap];
}

__global__ void prep_qkvw(const float* __restrict__ w, half_t* __restrict__ W16) {
  int idx = blockIdx.x * 256 + threadIdx.x;           // < 196608
  float v = w[idx];
  if (idx < 65536) v *= SCALEQ;                       // q rows pre-scaled
  W16[idx] = (half_t)v;
}

__global__ void prep_projw(const float* __restrict__ w, half_t* __restrict__ W16) {
  int idx = blockIdx.x * 256 + threadIdx.x;           // < 65536
  W16[idx] = (half_t)w[idx];
}

__global__ void prep_bias(const float* __restrict__ rpb, float* __restrict__ btab) {
  int idx = blockIdx.x * 256 + threadIdx.x;           // < 32768
  int hd = idx >> 12, n = (idx >> 6) & 63, m = idx & 63;
  int h1 = n >> 3, w1 = n & 7, h2 = m >> 3, w2 = m & 7;
  int ridx = (h1 - h2 + 7) * 15 + (w1 - w2 + 7);
  btab[idx] = rpb[ridx * 8 + hd];
}

__global__ void prep_xpad(const float* __restrict__ x, half_t* __restrict__ xpad) {
  __shared__ float tile[128 * 65];
  int bd = blockIdx.x, b = bd / 100, d = bd % 100;
  int t = threadIdx.x;
  for (int hf = 0; hf < 2; ++hf) {
    for (int i = 0; i < 32; ++i) {
      int idx = i * 256 + t, c = idx >> 6, hw = idx & 63;
      tile[c * 65 + hw] = x[(size_t)((b * 256 + hf * 128 + c) * 100 + d) * 64 + hw];
    }
    __syncthreads();
    for (int i = 0; i < 50; ++i) {
      int idx = i * 256 + t, cell = idx >> 7, c = idx & 127;
      int hh = cell / 10, ww = cell % 10;
      float v = 0.f;
      if (hh >= 1 && hh <= 8 && ww >= 1 && ww <= 8)
        v = tile[c * 65 + (hh - 1) * 8 + (ww - 1)];
      xpad[(size_t)(bd * 100 + cell) * 256 + hf * 128 + c] = (half_t)v;
    }
    __syncthreads();
  }
}

// ---------------- conv implicit GEMM (unchanged from round 1) ----------------
__global__ __launch_bounds__(256) void conv_kernel(
    const half_t* __restrict__ Wt, const half_t* __restrict__ xpad,
    const float* __restrict__ convb, half_t* __restrict__ xl) {
  __shared__ __align__(16) half_t Asm[128 * 64];
  __shared__ __align__(16) half_t Bsm[128 * 64];
  const int blk = blockIdx.x;
  const int o0 = (blk & 1) * 128;
  const int n0 = (blk >> 1) * 128;
  const int tid = threadIdx.x;
  const int wave = tid >> 6, lane = tid & 63;
  const int l15 = lane & 15, quad = lane >> 4;
  const int wm = wave >> 1, wn = wave & 1;
  const int srow = tid >> 3;
  const int cg = (tid & 7) ^ (srow & 7);

  int pixbase[4], arow[4];
#pragma unroll
  for (int i = 0; i < 4; ++i) {
    int P = n0 + srow + i * 32;
    int bd = P >> 6, hw = P & 63;
    pixbase[i] = (bd * 100 + (hw >> 3) * 10 + (hw & 7)) * 512 + cg * 16;
    arow[i] = (o0 + srow + i * 32) * 512 + cg * 16;
  }

  float4v acc[4][4];
#pragma unroll
  for (int mi = 0; mi < 4; ++mi)
#pragma unroll
    for (int ni = 0; ni < 4; ++ni) {
      float4v z = {0.f, 0.f, 0.f, 0.f};
      acc[mi][ni] = z;
    }

  const char* xpc = (const char*)xpad;
  for (int tap = 0; tap < 9; ++tap) {
    const char* wt = (const char*)Wt + tap * 131072;
    const int toff = ((tap / 3) * 10 + (tap % 3)) * 512;
    for (int c0 = 0; c0 < 512; c0 += 128) {
#pragma unroll
      for (int i = 0; i < 4; ++i) {
        GLDS16(wt + arow[i] + c0, (char*)Asm + i * 4096 + wave * 1024);
        GLDS16(xpc + pixbase[i] + toff + c0, (char*)Bsm + i * 4096 + wave * 1024);
      }
      __syncthreads();
#pragma unroll
      for (int kh = 0; kh < 2; ++kh) {
        half8 af[4], bf[4];
#pragma unroll
        for (int mi = 0; mi < 4; ++mi) {
          int r = wm * 64 + mi * 16 + l15;
          af[mi] = *(const half8*)&Asm[r * 64 + (((kh * 4 + quad) ^ (r & 7)) * 8)];
        }
#pragma unroll
        for (int ni = 0; ni < 4; ++ni) {
          int r = wn * 64 + ni * 16 + l15;
          bf[ni] = *(const half8*)&Bsm[r * 64 + (((kh * 4 + quad) ^ (r & 7)) * 8)];
        }
#pragma unroll
        for (int mi = 0; mi < 4; ++mi)
#pragma unroll
          for (int ni = 0; ni < 4; ++ni)
            acc[mi][ni] = __builtin_amdgcn_mfma_f32_16x16x32_f16(
                af[mi], bf[ni], acc[mi][ni], 0, 0, 0);
      }
      __syncthreads();
    }
  }
#pragma unroll
  for (int mi = 0; mi < 4; ++mi) {
    const int o4 = o0 + wm * 64 + mi * 16 + quad * 4;
    const float b0 = convb[o4], b1 = convb[o4 + 1], b2 = convb[o4 + 2], b3 = convb[o4 + 3];
#pragma unroll
    for (int ni = 0; ni < 4; ++ni) {
      const int P = n0 + wn * 64 + ni * 16 + l15;
      half4v h;
      h.x = (half_t)(acc[mi][ni].x + b0);
      h.y = (half_t)(acc[mi][ni].y + b1);
      h.z = (half_t)(acc[mi][ni].z + b2);
      h.w = (half_t)(acc[mi][ni].w + b3);
      *(half4v*)(xl + (size_t)P * 256 + o4) = h;
    }
  }
}

// ---------------- fused qkv + attention + proj ----------------
// One block per bd slice (64 pixels, 8 heads). Wave w owns heads 2w, 2w+1.
// LDS halves layout (155,648 B total):
//   qs:  [0,      20480)  q[8 hd][64 px][40]   (pad-40 rows)  -> later xa[64 px][264]
//   ks:  [20480,  40960)  k[8 hd][64 px][40]
//   vs:  [40960,  59392)  v[8 hd][32 hd][72]   (pad-72 rows)
//   xlp: [59392,  75776)  xl[64 px][256] XOR-swizzled 16B chunks
//   Ps:  [59392,  77824)  P per wave [64 n][72] (overwrites xlp after qkv barrier)
__global__ void fused_tail(
    const half_t* __restrict__ xlg, const half_t* __restrict__ qw,
    const float* __restrict__ qkvb, const half_t* __restrict__ pw,
    const float* __restrict__ projb, const float* __restrict__ btab,
    float* __restrict__ out32) {
  __shared__ __align__(16) half_t LS[77824];
  half_t* qs = LS;
  half_t* ks = LS + 20480;
  half_t* vs = LS + 40960;
  half_t* xlp = LS + 59392;
  half_t* xa = LS;  // over qs

  const int bd = blockIdx.x;
  const int tid = threadIdx.x;
  const int wave = tid >> 6, lane = tid & 63;
  const int l15 = lane & 15, quad = lane >> 4;

  // ---- stage xl[bd] into LDS, XOR-swizzled 16B chunks ----
  {
    const char* src = (const char*)(xlg + (size_t)bd * 64 * 256);
#pragma unroll
    for (int i = 0; i < 8; ++i) {
      int row = wave * 16 + i * 2 + (lane >> 5);
      int schunk = (lane & 31) ^ (row & 7);
      GLDS16(src + row * 512 + schunk * 16, (char*)xlp + (wave * 16 + i * 2) * 512);
    }
  }
  __syncthreads();

  // ---- qkv: 3 parts, each wave computes o-rows [wave*64, wave*64+64) ----
  for (int p = 0; p < 3; ++p) {
    const half_t* Wp = qw + p * 65536;
    float4v acc[4][4];
#pragma unroll
    for (int mi = 0; mi < 4; ++mi)
#pragma unroll
      for (int ni = 0; ni < 4; ++ni) {
        float4v z = {0.f, 0.f, 0.f, 0.f};
        acc[mi][ni] = z;
      }
#pragma unroll
    for (int kh = 0; kh < 8; ++kh) {
      half8 af[4], bf[4];
#pragma unroll
      for (int mi = 0; mi < 4; ++mi)
        af[mi] = *(const half8*)(Wp + (wave * 64 + mi * 16 + l15) * 256 + kh * 32 + quad * 8);
#pragma unroll
      for (int ni = 0; ni < 4; ++ni) {
        int r = ni * 16 + l15;
        bf[ni] = *(const half8*)&xlp[r * 256 + (((kh * 4 + quad) ^ (r & 7)) * 8)];
      }
#pragma unroll
      for (int mi = 0; mi < 4; ++mi)
#pragma unroll
        for (int ni = 0; ni < 4; ++ni)
          acc[mi][ni] = __builtin_amdgcn_mfma_f32_16x16x32_f16(
              af[mi], bf[ni], acc[mi][ni], 0, 0, 0);
    }
    // epilogue -> LDS
    const float sc = (p == 0) ? SCALEQ : 1.0f;
#pragma unroll
    for (int mi = 0; mi < 4; ++mi) {
      const int o4 = wave * 64 + mi * 16 + quad * 4;  // within part
      const int head = o4 >> 5, hd = o4 & 31;
      const float b0 = qkvb[p * 256 + o4] * sc, b1 = qkvb[p * 256 + o4 + 1] * sc;
      const float b2 = qkvb[p * 256 + o4 + 2] * sc, b3 = qkvb[p * 256 + o4 + 3] * sc;
#pragma unroll
      for (int ni = 0; ni < 4; ++ni) {
        const int n = ni * 16 + l15;
        const float v0 = acc[mi][ni].x + b0, v1 = acc[mi][ni].y + b1;
        const float v2 = acc[mi][ni].z + b2, v3 = acc[mi][ni].w + b3;
        if (p < 2) {
          half_t* base = (p == 0) ? qs : ks;
          half4v h = {(half_t)v0, (half_t)v1, (half_t)v2, (half_t)v3};
          *(half4v*)(base + head * 2560 + n * 40 + hd) = h;
        } else {
          half_t* vb = vs + head * 2304 + hd * 72 + n;
          vb[0] = (half_t)v0;
          vb[72] = (half_t)v1;
          vb[144] = (half_t)v2;
          vb[216] = (half_t)v3;
        }
      }
    }
  }
  __syncthreads();  // xlp dead; Ps may now overwrite it

  // ---- attention: wave w -> heads 2w, 2w+1 (self-written q/k/v) ----
  half_t* Pw = LS + 59392 + wave * 4608;  // 64 x 72 halves per wave
  float4v oa2[2][2][4];
#pragma unroll
  for (int hidx = 0; hidx < 2; ++hidx) {
    const int head = wave * 2 + hidx;
    const half_t* qp = qs + head * 2560;
    const half_t* kp = ks + head * 2560;
    const half_t* vp = vs + head * 2304;

    half8 aq[4], bk[4];
#pragma unroll
    for (int i = 0; i < 4; ++i) {
      aq[i] = *(const half8*)(qp + (i * 16 + l15) * 40 + quad * 8);
      bk[i] = *(const half8*)(kp + (i * 16 + l15) * 40 + quad * 8);
    }
    float4v s[4][4];
#pragma unroll
    for (int ni = 0; ni < 4; ++ni)
#pragma unroll
      for (int mi = 0; mi < 4; ++mi) {
        float4v z = {0.f, 0.f, 0.f, 0.f};
        s[ni][mi] = __builtin_amdgcn_mfma_f32_16x16x32_f16(aq[ni], bk[mi], z, 0, 0, 0);
      }
    const float* bh = btab + head * 4096;
#pragma unroll
    for (int ni = 0; ni < 4; ++ni)
#pragma unroll
      for (int i = 0; i < 4; ++i) {
        const int n = ni * 16 + quad * 4 + i;
#pragma unroll
        for (int mi = 0; mi < 4; ++mi) s[ni][mi][i] += bh[n * 64 + mi * 16 + l15];
      }
    float inv[4][4];
#pragma unroll
    for (int ni = 0; ni < 4; ++ni)
#pragma unroll
      for (int i = 0; i < 4; ++i) {
        float mx = fmaxf(fmaxf(s[ni][0][i], s[ni][1][i]), fmaxf(s[ni][2][i], s[ni][3][i]));
        for (int off = 1; off < 16; off <<= 1) mx = fmaxf(mx, __shfl_xor(mx, off));
        float sum = 0.f;
#pragma unroll
        for (int mi = 0; mi < 4; ++mi) {
          float e = __expf(s[ni][mi][i] - mx);
          s[ni][mi][i] = e;
          sum += e;
        }
        for (int off = 1; off < 16; off <<= 1) sum += __shfl_xor(sum, off);
        inv[ni][i] = 1.0f / sum;
      }
#pragma unroll
    for (int ni = 0; ni < 4; ++ni)
#pragma unroll
      for (int i = 0; i < 4; ++i) {
        const int n = ni * 16 + quad * 4 + i;
#pragma unroll
        for (int mi = 0; mi < 4; ++mi)
          Pw[n * 72 + mi * 16 + l15] = (half_t)(s[ni][mi][i] * inv[ni][i]);
      }
    // PV (same-wave LDS dependency; compiler inserts lgkmcnt waits)
    __builtin_amdgcn_s_waitcnt(0);  // ensure ds writes visible to own reads
    half8 av[2][2];
#pragma unroll
    for (int ci = 0; ci < 2; ++ci)
#pragma unroll
      for (int k2 = 0; k2 < 2; ++k2)
        av[ci][k2] = *(const half8*)(vp + (ci * 16 + l15) * 72 + k2 * 32 + quad * 8);
#pragma unroll
    for (int ci = 0; ci < 2; ++ci)
#pragma unroll
      for (int ni = 0; ni < 4; ++ni) {
        float4v z = {0.f, 0.f, 0.f, 0.f};
        oa2[hidx][ci][ni] = z;
      }
#pragma unroll
    for (int ni = 0; ni < 4; ++ni)
#pragma unroll
      for (int k2 = 0; k2 < 2; ++k2) {
        half8 bp = *(const half8*)&Pw[(ni * 16 + l15) * 72 + k2 * 32 + quad * 8];
#pragma unroll
        for (int ci = 0; ci < 2; ++ci)
          oa2[hidx][ci][ni] = __builtin_amdgcn_mfma_f32_16x16x32_f16(
              av[ci][k2], bp, oa2[hidx][ci][ni], 0, 0, 0);
      }
  }
  __syncthreads();  // all q/k/v reads done; qs region becomes xa

  // ---- xa -> LDS [px][264] ----
#pragma unroll
  for (int hidx = 0; hidx < 2; ++hidx) {
    const int ch0 = (wave * 2 + hidx) * 32;
#pragma unroll
    for (int ci = 0; ci < 2; ++ci)
#pragma unroll
      for (int ni = 0; ni < 4; ++ni) {
        half4v h = {(half_t)oa2[hidx][ci][ni].x, (half_t)oa2[hidx][ci][ni].y,
                    (half_t)oa2[hidx][ci][ni].z, (half_t)oa2[hidx][ci][ni].w};
        *(half4v*)(xa + (ni * 16 + l15) * 264 + ch0 + ci * 16 + quad * 4) = h;
      }
  }
  __syncthreads();

  // ---- proj: out[256 o][64 px], wave owns o-rows [wave*64, +64) ----
  {
    float4v acc[4][4];
#pragma unroll
    for (int mi = 0; mi < 4; ++mi)
#pragma unroll
      for (int ni = 0; ni < 4; ++ni) {
        float4v z = {0.f, 0.f, 0.f, 0.f};
        acc[mi][ni] = z;
      }
#pragma unroll
    for (int kh = 0; kh < 8; ++kh) {
      half8 af[4], bf[4];
#pragma unroll
      for (int mi = 0; mi < 4; ++mi)
        af[mi] = *(const half8*)(pw + (wave * 64 + mi * 16 + l15) * 256 + kh * 32 + quad * 8);
#pragma unroll
      for (int ni = 0; ni < 4; ++ni)
        bf[ni] = *(const half8*)&xa[(ni * 16 + l15) * 264 + kh * 32 + quad * 8];
#pragma unroll
      for (int mi = 0; mi < 4; ++mi)
#pragma unroll
        for (int ni = 0; ni < 4; ++ni)
          acc[mi][ni] = __builtin_amdgcn_mfma_f32_16x16x32_f16(
              af[mi], bf[ni], acc[mi][ni], 0, 0, 0);
    }
    const int b = bd / 100, d = bd % 100;
    const size_t base0 = (size_t)b * 1638400 + (size_t)d * 64;
#pragma unroll
    for (int mi = 0; mi < 4; ++mi) {
      const int o4 = wave * 64 + mi * 16 + quad * 4;
      const float b0 = projb[o4], b1 = projb[o4 + 1], b2 = projb[o4 + 2], b3 = projb[o4 + 3];
#pragma unroll
      for (int ni = 0; ni < 4; ++ni) {
        const int px = ni * 16 + l15;
        out32[base0 + (size_t)(o4 + 0) * 6400 + px] = acc[mi][ni].x + b0;
        out32[base0 + (size_t)(o4 + 1) * 6400 + px] = acc[mi][ni].y + b1;
        out32[base0 + (size_t)(o4 + 2) * 6400 + px] = acc[mi][ni].z + b2;
        out32[base0 + (size_t)(o4 + 3) * 6400 + px] = acc[mi][ni].w + b3;
      }
    }
  }
}

// ---------------- launch ----------------
extern "C" void kernel_launch(void* const* d_in, const int* in_sizes, int n_in,
                              void* d_out, int out_size, void* d_ws, size_t ws_size,
                              hipStream_t stream) {
  const float* x        = (const float*)d_in[0];
  const float* dwconv_w = (const float*)d_in[1];
  const float* dwconv_b = (const float*)d_in[2];
  const float* qkv_w    = (const float*)d_in[3];
  const float* qkv_b    = (const float*)d_in[4];
  const float* proj_w   = (const float*)d_in[5];
  const float* proj_b   = (const float*)d_in[6];
  const float* rpb      = (const float*)d_in[7];
  float* out = (float*)d_out;

  char* ws = (char*)d_ws;
  size_t off = 0;
  half_t* xpad = (half_t*)(ws + off); off += 40960000;   // 800*100*256 fp16
  half_t* xl   = (half_t*)(ws + off); off += 26214400;   // 51200*256 fp16
  half_t* Wt   = (half_t*)(ws + off); off += 1179648;    // [9][256][256]
  half_t* qw16 = (half_t*)(ws + off); off += 393216;
  half_t* pw16 = (half_t*)(ws + off); off += 131072;
  float*  btab = (float*)(ws + off);  off += 131072;     // [8][64][64]

  prep_convw<<<2304, 256, 0, stream>>>(dwconv_w, Wt);
  prep_qkvw<<<768, 256, 0, stream>>>(qkv_w, qw16);
  prep_projw<<<256, 256, 0, stream>>>(proj_w, pw16);
  prep_bias<<<128, 256, 0, stream>>>(rpb, btab);
  prep_xpad<<<800, 256, 0, stream>>>(x, xpad);

  conv_kernel<<<800, 256, 0, stream>>>(Wt, xpad, dwconv_b, xl);
  fused_tail<<<800, 256, 0, stream>>>(xl, qw16, qkv_b, pw16, proj_b, btab, out);
}

// Round 3
// 322.320 us; speedup vs baseline: 1.4064x; 1.4064x over previous
//
#include <hip/hip_runtime.h>
#include <cstdint>
#include <cstddef>

// ---------------- problem constants ----------------
#define SCALEQ 0.17677669529663689f // 32^-0.5

typedef _Float16 half_t;
typedef _Float16 half8   __attribute__((ext_vector_type(8)));
typedef _Float16 half4v  __attribute__((ext_vector_type(4)));
typedef float    float4v __attribute__((ext_vector_type(4)));
typedef float    float2v __attribute__((ext_vector_type(2)));

#define GLDS16(gp, lp)                                                        \
  __builtin_amdgcn_global_load_lds(                                           \
      (const __attribute__((address_space(1))) void*)(gp),                    \
      (__attribute__((address_space(3))) void*)(lp), 16, 0, 0)

// ---------------- prep kernels ----------------
__global__ void prep_convw(const float* __restrict__ w, half_t* __restrict__ Wt) {
  int idx = blockIdx.x * 256 + threadIdx.x;           // < 589824
  int tap = idx >> 16, rem = idx & 65535;
  int o = rem >> 8, c = rem & 255;
  Wt[idx] = (half_t)w[(o * 256 + c) * 9 + tap];
}

__global__ void prep_qkvw(const float* __restrict__ w, half_t* __restrict__ W16) {
  int idx = blockIdx.x * 256 + threadIdx.x;           // < 196608
  float v = w[idx];
  if (idx < 65536) v *= SCALEQ;                       // q rows pre-scaled
  W16[idx] = (half_t)v;
}

__global__ void prep_projw(const float* __restrict__ w, half_t* __restrict__ W16) {
  int idx = blockIdx.x * 256 + threadIdx.x;           // < 65536
  W16[idx] = (half_t)w[idx];
}

__global__ void prep_bias(const float* __restrict__ rpb, float* __restrict__ btab) {
  int idx = blockIdx.x * 256 + threadIdx.x;           // < 32768
  int hd = idx >> 12, n = (idx >> 6) & 63, m = idx & 63;
  int h1 = n >> 3, w1 = n & 7, h2 = m >> 3, w2 = m & 7;
  int ridx = (h1 - h2 + 7) * 15 + (w1 - w2 + 7);
  btab[idx] = rpb[ridx * 8 + hd];
}

__global__ void prep_xpad(const float* __restrict__ x, half_t* __restrict__ xpad) {
  __shared__ float tile[128 * 65];
  int bd = blockIdx.x, b = bd / 100, d = bd % 100;
  int t = threadIdx.x;
  for (int hf = 0; hf < 2; ++hf) {
    for (int i = 0; i < 32; ++i) {
      int idx = i * 256 + t, c = idx >> 6, hw = idx & 63;
      tile[c * 65 + hw] = x[(size_t)((b * 256 + hf * 128 + c) * 100 + d) * 64 + hw];
    }
    __syncthreads();
    for (int i = 0; i < 50; ++i) {
      int idx = i * 256 + t, cell = idx >> 7, c = idx & 127;
      int hh = cell / 10, ww = cell % 10;
      float v = 0.f;
      if (hh >= 1 && hh <= 8 && ww >= 1 && ww <= 8)
        v = tile[c * 65 + (hh - 1) * 8 + (ww - 1)];
      xpad[(size_t)(bd * 100 + cell) * 256 + hf * 128 + c] = (half_t)v;
    }
    __syncthreads();
  }
}

// ---------------- conv implicit GEMM (unchanged, verified) ----------------
__global__ __launch_bounds__(256) void conv_kernel(
    const half_t* __restrict__ Wt, const half_t* __restrict__ xpad,
    const float* __restrict__ convb, half_t* __restrict__ xl) {
  __shared__ __align__(16) half_t Asm[128 * 64];
  __shared__ __align__(16) half_t Bsm[128 * 64];
  const int blk = blockIdx.x;
  const int o0 = (blk & 1) * 128;
  const int n0 = (blk >> 1) * 128;
  const int tid = threadIdx.x;
  const int wave = tid >> 6, lane = tid & 63;
  const int l15 = lane & 15, quad = lane >> 4;
  const int wm = wave >> 1, wn = wave & 1;
  const int srow = tid >> 3;
  const int cg = (tid & 7) ^ (srow & 7);

  int pixbase[4], arow[4];
#pragma unroll
  for (int i = 0; i < 4; ++i) {
    int P = n0 + srow + i * 32;
    int bd = P >> 6, hw = P & 63;
    pixbase[i] = (bd * 100 + (hw >> 3) * 10 + (hw & 7)) * 512 + cg * 16;
    arow[i] = (o0 + srow + i * 32) * 512 + cg * 16;
  }

  float4v acc[4][4];
#pragma unroll
  for (int mi = 0; mi < 4; ++mi)
#pragma unroll
    for (int ni = 0; ni < 4; ++ni) {
      float4v z = {0.f, 0.f, 0.f, 0.f};
      acc[mi][ni] = z;
    }

  const char* xpc = (const char*)xpad;
  for (int tap = 0; tap < 9; ++tap) {
    const char* wt = (const char*)Wt + tap * 131072;
    const int toff = ((tap / 3) * 10 + (tap % 3)) * 512;
    for (int c0 = 0; c0 < 512; c0 += 128) {
#pragma unroll
      for (int i = 0; i < 4; ++i) {
        GLDS16(wt + arow[i] + c0, (char*)Asm + i * 4096 + wave * 1024);
        GLDS16(xpc + pixbase[i] + toff + c0, (char*)Bsm + i * 4096 + wave * 1024);
      }
      __syncthreads();
#pragma unroll
      for (int kh = 0; kh < 2; ++kh) {
        half8 af[4], bf[4];
#pragma unroll
        for (int mi = 0; mi < 4; ++mi) {
          int r = wm * 64 + mi * 16 + l15;
          af[mi] = *(const half8*)&Asm[r * 64 + (((kh * 4 + quad) ^ (r & 7)) * 8)];
        }
#pragma unroll
        for (int ni = 0; ni < 4; ++ni) {
          int r = wn * 64 + ni * 16 + l15;
          bf[ni] = *(const half8*)&Bsm[r * 64 + (((kh * 4 + quad) ^ (r & 7)) * 8)];
        }
#pragma unroll
        for (int mi = 0; mi < 4; ++mi)
#pragma unroll
          for (int ni = 0; ni < 4; ++ni)
            acc[mi][ni] = __builtin_amdgcn_mfma_f32_16x16x32_f16(
                af[mi], bf[ni], acc[mi][ni], 0, 0, 0);
      }
      __syncthreads();
    }
  }
#pragma unroll
  for (int mi = 0; mi < 4; ++mi) {
    const int o4 = o0 + wm * 64 + mi * 16 + quad * 4;
    const float b0 = convb[o4], b1 = convb[o4 + 1], b2 = convb[o4 + 2], b3 = convb[o4 + 3];
#pragma unroll
    for (int ni = 0; ni < 4; ++ni) {
      const int P = n0 + wn * 64 + ni * 16 + l15;
      half4v h;
      h.x = (half_t)(acc[mi][ni].x + b0);
      h.y = (half_t)(acc[mi][ni].y + b1);
      h.z = (half_t)(acc[mi][ni].z + b2);
      h.w = (half_t)(acc[mi][ni].w + b3);
      *(half4v*)(xl + (size_t)P * 256 + o4) = h;
    }
  }
}

// ---------------- qkv GEMM ----------------
// M=768 (q|k|v) x N=51200 px, K=256. For part 2 (v) the operand roles are
// swapped so D=[px][o] and the store is a contiguous half4v (4 px) into
// vt[bd][h][hd][n] -- no 2B scatter.
__global__ __launch_bounds__(256) void qkv_kernel(
    const half_t* __restrict__ Wq, const half_t* __restrict__ xlg,
    const float* __restrict__ qkvb, half_t* __restrict__ qt,
    half_t* __restrict__ kt, half_t* __restrict__ vt) {
  __shared__ __align__(16) half_t Asm[128 * 64];
  __shared__ __align__(16) half_t Bsm[128 * 64];
  const int blk = blockIdx.x;
  const int o0 = (blk % 6) * 128;
  const int n0 = (blk / 6) * 128;
  const int part = o0 >> 8;                  // 0=q 1=k 2=v (block-uniform)
  const int tid = threadIdx.x;
  const int wave = tid >> 6, lane = tid & 63;
  const int l15 = lane & 15, quad = lane >> 4;
  const int wm = wave >> 1, wn = wave & 1;
  const int srow = tid >> 3;
  const int cg = (tid & 7) ^ (srow & 7);

  int arow[4], brow[4];
#pragma unroll
  for (int i = 0; i < 4; ++i) {
    arow[i] = (o0 + srow + i * 32) * 512 + cg * 16;
    brow[i] = (n0 + srow + i * 32) * 512 + cg * 16;
  }
  float4v acc[4][4];
#pragma unroll
  for (int mi = 0; mi < 4; ++mi)
#pragma unroll
    for (int ni = 0; ni < 4; ++ni) {
      float4v z = {0.f, 0.f, 0.f, 0.f};
      acc[mi][ni] = z;
    }

  // part<2: A-frags from Asm (W), B-frags from Bsm (xl)  -> D[o][px]
  // part==2: swapped                                      -> D[px][o]
  const half_t* Afr = (part == 2) ? Bsm : Asm;
  const half_t* Bfr = (part == 2) ? Asm : Bsm;

  for (int c0 = 0; c0 < 512; c0 += 128) {
#pragma unroll
    for (int i = 0; i < 4; ++i) {
      GLDS16((const char*)Wq + arow[i] + c0, (char*)Asm + i * 4096 + wave * 1024);
      GLDS16((const char*)xlg + brow[i] + c0, (char*)Bsm + i * 4096 + wave * 1024);
    }
    __syncthreads();
#pragma unroll
    for (int kh = 0; kh < 2; ++kh) {
      half8 af[4], bf[4];
#pragma unroll
      for (int mi = 0; mi < 4; ++mi) {
        int r = wm * 64 + mi * 16 + l15;
        af[mi] = *(const half8*)&Afr[r * 64 + (((kh * 4 + quad) ^ (r & 7)) * 8)];
      }
#pragma unroll
      for (int ni = 0; ni < 4; ++ni) {
        int r = wn * 64 + ni * 16 + l15;
        bf[ni] = *(const half8*)&Bfr[r * 64 + (((kh * 4 + quad) ^ (r & 7)) * 8)];
      }
#pragma unroll
      for (int mi = 0; mi < 4; ++mi)
#pragma unroll
        for (int ni = 0; ni < 4; ++ni)
          acc[mi][ni] = __builtin_amdgcn_mfma_f32_16x16x32_f16(
              af[mi], bf[ni], acc[mi][ni], 0, 0, 0);
    }
    __syncthreads();
  }

  if (part < 2) {
    half_t* base = (part == 0) ? qt : kt;
    const float sc = (part == 0) ? SCALEQ : 1.0f;
#pragma unroll
    for (int mi = 0; mi < 4; ++mi) {
      const int og = o0 + wm * 64 + mi * 16 + quad * 4;   // global o in [0,768)
      const int oc = og & 255, head = oc >> 5, hd = oc & 31;
      const float b0 = qkvb[og] * sc, b1 = qkvb[og + 1] * sc;
      const float b2 = qkvb[og + 2] * sc, b3 = qkvb[og + 3] * sc;
#pragma unroll
      for (int ni = 0; ni < 4; ++ni) {
        const int P = n0 + wn * 64 + ni * 16 + l15;
        const int bd = P >> 6, nn = P & 63;
        half4v h;
        h.x = (half_t)(acc[mi][ni].x + b0);
        h.y = (half_t)(acc[mi][ni].y + b1);
        h.z = (half_t)(acc[mi][ni].z + b2);
        h.w = (half_t)(acc[mi][ni].w + b3);
        *(half4v*)(base + ((size_t)(bd * 8 + head) * 64 + nn) * 32 + hd) = h;
      }
    }
  } else {
#pragma unroll
    for (int mi = 0; mi < 4; ++mi) {
      const int px = n0 + wm * 64 + mi * 16 + quad * 4;   // 4 consecutive px
      const int bd = px >> 6, nn = px & 63;
#pragma unroll
      for (int ni = 0; ni < 4; ++ni) {
        const int oc = wn * 64 + ni * 16 + l15;           // o within part (0..127 + o0&255)
        const int ov = (o0 & 255) + oc, head = ov >> 5, hd = ov & 31;
        const float bb = qkvb[512 + ov];
        half4v h;
        h.x = (half_t)(acc[mi][ni].x + bb);
        h.y = (half_t)(acc[mi][ni].y + bb);
        h.z = (half_t)(acc[mi][ni].z + bb);
        h.w = (half_t)(acc[mi][ni].w + bb);
        *(half4v*)(vt + ((size_t)(bd * 8 + head) * 32 + hd) * 64 + nn) = h;
      }
    }
  }
}

// ---------------- attention (round-1 verified) ----------------
__global__ __launch_bounds__(256) void attn_kernel(
    const half_t* __restrict__ qt, const half_t* __restrict__ kt,
    const half_t* __restrict__ vt, const float* __restrict__ btab,
    half_t* __restrict__ xa) {
  __shared__ __align__(16) half_t Pl[4][64 * 72];
  const int blk = blockIdx.x;
  const int bd = blk >> 1;
  const int wave = threadIdx.x >> 6, lane = threadIdx.x & 63;
  const int head = (blk & 1) * 4 + wave;
  const int l15 = lane & 15, quad = lane >> 4;
  const half_t* qp = qt + (size_t)(bd * 8 + head) * 2048;
  const half_t* kp = kt + (size_t)(bd * 8 + head) * 2048;
  const half_t* vp = vt + (size_t)(bd * 8 + head) * 2048;

  half8 aq[4], bk[4];
#pragma unroll
  for (int i = 0; i < 4; ++i) {
    aq[i] = *(const half8*)(qp + (i * 16 + l15) * 32 + quad * 8);
    bk[i] = *(const half8*)(kp + (i * 16 + l15) * 32 + quad * 8);
  }
  float4v s[4][4];
#pragma unroll
  for (int ni = 0; ni < 4; ++ni)
#pragma unroll
    for (int mi = 0; mi < 4; ++mi) {
      float4v z = {0.f, 0.f, 0.f, 0.f};
      s[ni][mi] = __builtin_amdgcn_mfma_f32_16x16x32_f16(aq[ni], bk[mi], z, 0, 0, 0);
    }
  const float* bh = btab + head * 4096;
#pragma unroll
  for (int ni = 0; ni < 4; ++ni)
#pragma unroll
    for (int i = 0; i < 4; ++i) {
      const int n = ni * 16 + quad * 4 + i;
#pragma unroll
      for (int mi = 0; mi < 4; ++mi) s[ni][mi][i] += bh[n * 64 + mi * 16 + l15];
    }
  float inv[4][4];
#pragma unroll
  for (int ni = 0; ni < 4; ++ni)
#pragma unroll
    for (int i = 0; i < 4; ++i) {
      float mx = fmaxf(fmaxf(s[ni][0][i], s[ni][1][i]), fmaxf(s[ni][2][i], s[ni][3][i]));
      for (int off = 1; off < 16; off <<= 1) mx = fmaxf(mx, __shfl_xor(mx, off));
      float sum = 0.f;
#pragma unroll
      for (int mi = 0; mi < 4; ++mi) {
        float e = __expf(s[ni][mi][i] - mx);
        s[ni][mi][i] = e;
        sum += e;
      }
      for (int off = 1; off < 16; off <<= 1) sum += __shfl_xor(sum, off);
      inv[ni][i] = 1.0f / sum;
    }
#pragma unroll
  for (int ni = 0; ni < 4; ++ni)
#pragma unroll
    for (int i = 0; i < 4; ++i) {
      const int n = ni * 16 + quad * 4 + i;
#pragma unroll
      for (int mi = 0; mi < 4; ++mi)
        Pl[wave][n * 72 + mi * 16 + l15] = (half_t)(s[ni][mi][i] * inv[ni][i]);
    }
  __syncthreads();
  half8 av[2][2];
#pragma unroll
  for (int ci = 0; ci < 2; ++ci)
#pragma unroll
    for (int k2 = 0; k2 < 2; ++k2)
      av[ci][k2] = *(const half8*)(vp + (ci * 16 + l15) * 64 + k2 * 32 + quad * 8);
  float4v oa[2][4];
#pragma unroll
  for (int ci = 0; ci < 2; ++ci)
#pragma unroll
    for (int ni = 0; ni < 4; ++ni) {
      float4v z = {0.f, 0.f, 0.f, 0.f};
      oa[ci][ni] = z;
    }
#pragma unroll
  for (int ni = 0; ni < 4; ++ni)
#pragma unroll
    for (int k2 = 0; k2 < 2; ++k2) {
      half8 bp = *(const half8*)&Pl[wave][(ni * 16 + l15) * 72 + k2 * 32 + quad * 8];
#pragma unroll
      for (int ci = 0; ci < 2; ++ci)
        oa[ci][ni] = __builtin_amdgcn_mfma_f32_16x16x32_f16(av[ci][k2], bp, oa[ci][ni], 0, 0, 0);
    }
#pragma unroll
  for (int ci = 0; ci < 2; ++ci)
#pragma unroll
    for (int ni = 0; ni < 4; ++ni) {
      half4v h = {(half_t)oa[ci][ni].x, (half_t)oa[ci][ni].y,
                  (half_t)oa[ci][ni].z, (half_t)oa[ci][ni].w};
      *(half4v*)(xa + (size_t)(bd * 64 + ni * 16 + l15) * 256 + head * 32 + ci * 16 + quad * 4) = h;
    }
}

// ---------------- proj GEMM with transposed fp32 epilogue ----------------
// D tile [128 o][128 px]; epilogue routes acc through an LDS fp32 tile
// (64 rows x 130 floats, 2 wm-rounds) so global stores are full 256B rows.
__global__ __launch_bounds__(256) void proj_kernel(
    const half_t* __restrict__ Wp, const half_t* __restrict__ xag,
    const float* __restrict__ projb, float* __restrict__ out32) {
  __shared__ __align__(16) char LS[133120 / 4];  // 33280 B: aliases Asm|Bsm then T
  half_t* Asm = (half_t*)LS;
  half_t* Bsm = (half_t*)(LS + 16384);
  float* T = (float*)LS;
  const int blk = blockIdx.x;
  const int o0 = (blk & 1) * 128;
  const int n0 = (blk >> 1) * 128;
  const int tid = threadIdx.x;
  const int wave = tid >> 6, lane = tid & 63;
  const int l15 = lane & 15, quad = lane >> 4;
  const int wm = wave >> 1, wn = wave & 1;
  const int srow = tid >> 3;
  const int cg = (tid & 7) ^ (srow & 7);

  int arow[4], brow[4];
#pragma unroll
  for (int i = 0; i < 4; ++i) {
    arow[i] = (o0 + srow + i * 32) * 512 + cg * 16;
    brow[i] = (n0 + srow + i * 32) * 512 + cg * 16;
  }
  float4v acc[4][4];
#pragma unroll
  for (int mi = 0; mi < 4; ++mi)
#pragma unroll
    for (int ni = 0; ni < 4; ++ni) {
      float4v z = {0.f, 0.f, 0.f, 0.f};
      acc[mi][ni] = z;
    }

  for (int c0 = 0; c0 < 512; c0 += 128) {
#pragma unroll
    for (int i = 0; i < 4; ++i) {
      GLDS16((const char*)Wp + arow[i] + c0, (char*)Asm + i * 4096 + wave * 1024);
      GLDS16((const char*)xag + brow[i] + c0, (char*)Bsm + i * 4096 + wave * 1024);
    }
    __syncthreads();
#pragma unroll
    for (int kh = 0; kh < 2; ++kh) {
      half8 af[4], bf[4];
#pragma unroll
      for (int mi = 0; mi < 4; ++mi) {
        int r = wm * 64 + mi * 16 + l15;
        af[mi] = *(const half8*)&Asm[r * 64 + (((kh * 4 + quad) ^ (r & 7)) * 8)];
      }
#pragma unroll
      for (int ni = 0; ni < 4; ++ni) {
        int r = wn * 64 + ni * 16 + l15;
        bf[ni] = *(const half8*)&Bsm[r * 64 + (((kh * 4 + quad) ^ (r & 7)) * 8)];
      }
#pragma unroll
      for (int mi = 0; mi < 4; ++mi)
#pragma unroll
        for (int ni = 0; ni < 4; ++ni)
          acc[mi][ni] = __builtin_amdgcn_mfma_f32_16x16x32_f16(
              af[mi], bf[ni], acc[mi][ni], 0, 0, 0);
    }
    __syncthreads();
  }

  // lane-constant output base (bd slice + px pair)
  const int bdg = (n0 >> 6) + (lane >> 5);
  const int b = bdg / 100, d = bdg % 100;
  const int px = (lane * 2) & 63;
  const size_t gbase = (size_t)b * 1638400 + (size_t)d * 64 + px;

  for (int r = 0; r < 2; ++r) {
    if (wm == r) {
#pragma unroll
      for (int mi = 0; mi < 4; ++mi)
#pragma unroll
        for (int ni = 0; ni < 4; ++ni)
#pragma unroll
          for (int iv = 0; iv < 4; ++iv)
            T[(mi * 16 + quad * 4 + iv) * 130 + wn * 64 + ni * 16 + l15] = acc[mi][ni][iv];
    }
    __syncthreads();
#pragma unroll
    for (int i = 0; i < 16; ++i) {
      const int orow = i * 4 + wave;                     // 0..63
      const int o = o0 + r * 64 + orow;
      float2v vv = *(const float2v*)&T[orow * 130 + lane * 2];
      const float bb = projb[o];
      vv.x += bb;
      vv.y += bb;
      *(float2v*)&out32[gbase + (size_t)o * 6400] = vv;
    }
    __syncthreads();
  }
}

// ---------------- launch ----------------
extern "C" void kernel_launch(void* const* d_in, const int* in_sizes, int n_in,
                              void* d_out, int out_size, void* d_ws, size_t ws_size,
                              hipStream_t stream) {
  const float* x        = (const float*)d_in[0];
  const float* dwconv_w = (const float*)d_in[1];
  const float* dwconv_b = (const float*)d_in[2];
  const float* qkv_w    = (const float*)d_in[3];
  const float* qkv_b    = (const float*)d_in[4];
  const float* proj_w   = (const float*)d_in[5];
  const float* proj_b   = (const float*)d_in[6];
  const float* rpb      = (const float*)d_in[7];
  float* out = (float*)d_out;

  char* ws = (char*)d_ws;
  size_t off = 0;
  half_t* xpad = (half_t*)(ws + off); off += 40960000;   // 800*100*256 fp16
  half_t* xl   = (half_t*)(ws + off); off += 26214400;   // 51200*256 fp16
  half_t* qt   = (half_t*)(ws + off); off += 26214400;   // [bd][h][n][hd]
  half_t* kt   = (half_t*)(ws + off); off += 26214400;   // [bd][h][n][hd]
  half_t* vt   = (half_t*)(ws + off); off += 26214400;   // [bd][h][hd][n]
  half_t* xa   = (half_t*)(ws + off); off += 26214400;   // [p][c]
  half_t* Wt   = (half_t*)(ws + off); off += 1179648;    // [9][256][256]
  half_t* qw16 = (half_t*)(ws + off); off += 393216;
  half_t* pw16 = (half_t*)(ws + off); off += 131072;
  float*  btab = (float*)(ws + off);  off += 131072;     // [8][64][64]

  prep_convw<<<2304, 256, 0, stream>>>(dwconv_w, Wt);
  prep_qkvw<<<768, 256, 0, stream>>>(qkv_w, qw16);
  prep_projw<<<256, 256, 0, stream>>>(proj_w, pw16);
  prep_bias<<<128, 256, 0, stream>>>(rpb, btab);
  prep_xpad<<<800, 256, 0, stream>>>(x, xpad);

  conv_kernel<<<800, 256, 0, stream>>>(Wt, xpad, dwconv_b, xl);
  qkv_kernel<<<2400, 256, 0, stream>>>(qw16, xl, qkv_b, qt, kt, vt);
  attn_kernel<<<1600, 256, 0, stream>>>(qt, kt, vt, btab, xa);
  proj_kernel<<<800, 256, 0, stream>>>(pw16, xa, proj_b, out);
}